// Round 4
// baseline (485.670 us; speedup 1.0000x reference)
//
#include <hip/hip_runtime.h>
#include <stdint.h>

// out = relu(A) * mask(top-64 per row), A: 8192x8192 fp32. Exact semantics
// (bit-exact threshold + lowest-index-first tie handling, matching
// lax.top_k + scatter).
//
// One block per row; values live in registers (16/thread @ BLOCK=512).
//  1) row max (shuffle reduce + 1 atomicMax)
//  2) 4-binade exponent window count -> candidate cut (~190 of 8192 survive)
//  3) compact candidates to LDS; all-pairs rank count (uint4 LDS broadcast)
//     -> exact 64th-largest bit pattern T + tie count. No hot-path histograms.
//  4) masked write from registers; exact lowest-index tie fixup
// Cold fallbacks (<K positives; window widen; C>CAP full radix) keep it exact
// for arbitrary inputs; none taken for normal data.

constexpr int N      = 8192;
constexpr int K      = 64;
constexpr int BLOCK  = 512;
constexpr int VPT    = N / BLOCK;   // 16 values/thread
constexpr int V4     = VPT / 4;     // 4 float4/thread
constexpr int CAP    = 1024;        // candidate list capacity (2*BLOCK)
constexpr int EQ_CAP = 256;

typedef float  fx4 __attribute__((ext_vector_type(4)));   // native vec for NT load

__device__ __forceinline__ uint32_t wave_reduce_add(uint32_t x) {
    #pragma unroll
    for (int d = 32; d >= 1; d >>= 1) x += __shfl_down(x, d, 64);
    return x;   // valid in lane 0
}

// wave 0 only: hist256 = 256 summed bins; pick digit at `shift` (cold path).
__device__ __forceinline__ void scan_pick(const uint32_t* hist256,
                                          uint32_t* s_prefix, uint32_t* s_k,
                                          int shift, int lane) {
    uint32_t k  = *s_k;
    uint32_t h0 = hist256[4 * lane + 0];
    uint32_t h1 = hist256[4 * lane + 1];
    uint32_t h2 = hist256[4 * lane + 2];
    uint32_t h3 = hist256[4 * lane + 3];
    uint32_t suf = h0 + h1 + h2 + h3;
    #pragma unroll
    for (int d = 1; d < 64; d <<= 1) {
        uint32_t o = __shfl_down(suf, d, 64);
        if (lane + d < 64) suf += o;
    }
    unsigned long long m = __ballot(suf >= k);
    int cl = 63 - __builtin_clzll(m);
    if (lane == cl) {
        uint32_t S0 = suf, S1 = S0 - h0, S2 = S1 - h1, S3 = S2 - h2;
        int b; uint32_t Sb, hb;
        if      (S3 >= k) { b = 3; Sb = S3; hb = h3; }
        else if (S2 >= k) { b = 2; Sb = S2; hb = h2; }
        else if (S1 >= k) { b = 1; Sb = S1; hb = h1; }
        else              { b = 0; Sb = S0; hb = h0; }
        *s_prefix |= (uint32_t)(4 * lane + b) << shift;
        *s_k = k - (Sb - hb);
    }
}

__global__ __launch_bounds__(BLOCK, 6) void topk_row_kernel(
    const float* __restrict__ A, float* __restrict__ out)
{
    __shared__ uint32_t list[CAP];
    __shared__ uint32_t hist[4][256];   // cold path only
    __shared__ uint32_t s_eq[EQ_CAP];
    __shared__ uint32_t s_wred[8];
    __shared__ uint32_t s_B[5];
    __shared__ uint32_t s_max, s_listcnt, s_cnt, s_mode, s_C, s_ecut, s_T, s_need;

    const int tid  = threadIdx.x;
    const int wave = tid >> 6;
    const int lane = tid & 63;
    const int row  = blockIdx.x;

    const fx4* rowp = reinterpret_cast<const fx4*>(A + (size_t)row * N);
    float4*    outp = reinterpret_cast<float4*>(out + (size_t)row * N);

    if (tid == 0) {
        s_max = 0; s_listcnt = 0; s_cnt = 0; s_mode = 0;
        s_T = 0xFFFFFFFFu; s_need = 0;
    }
    if (tid < 5) s_B[tid] = 0;

    // ---- load + relu into registers (uint order == float order for >= 0) ----
    uint32_t v[VPT];
    #pragma unroll
    for (int j = 0; j < V4; ++j) {
        fx4 f = __builtin_nontemporal_load(&rowp[tid + j * BLOCK]);
        v[4*j+0] = (f.x > 0.f) ? __float_as_uint(f.x) : 0u;
        v[4*j+1] = (f.y > 0.f) ? __float_as_uint(f.y) : 0u;
        v[4*j+2] = (f.z > 0.f) ? __float_as_uint(f.z) : 0u;
        v[4*j+3] = (f.w > 0.f) ? __float_as_uint(f.w) : 0u;
    }

    // ---- row max ----
    uint32_t mx = 0;
    #pragma unroll
    for (int j = 0; j < VPT; ++j) mx = (v[j] > mx) ? v[j] : mx;
    #pragma unroll
    for (int d = 32; d >= 1; d >>= 1) {
        uint32_t o = __shfl_down(mx, d, 64);
        mx = (o > mx) ? o : mx;
    }
    __syncthreads();                               // B1: init visible
    if (lane == 0) atomicMax(&s_max, mx);
    __syncthreads();                               // B2
    const uint32_t expM = s_max >> 23;

    // ---- 4-binade window count (packed register counters) ----
    {
        uint32_t p01 = 0, p23 = 0, cp = 0;
        #pragma unroll
        for (int j = 0; j < VPT; ++j) {
            uint32_t x = v[j];
            if (x != 0u) {
                uint32_t d = expM - (x >> 23);
                cp  += 1u;
                p01 += (d == 0u ? 1u : 0u) + (d == 1u ? 0x10000u : 0u);
                p23 += (d == 2u ? 1u : 0u) + (d == 3u ? 0x10000u : 0u);
            }
        }
        p01 = wave_reduce_add(p01);
        p23 = wave_reduce_add(p23);
        cp  = wave_reduce_add(cp);
        if (lane == 0) {
            atomicAdd(&s_B[0], p01 & 0xFFFFu);
            atomicAdd(&s_B[1], p01 >> 16);
            atomicAdd(&s_B[2], p23 & 0xFFFFu);
            atomicAdd(&s_B[3], p23 >> 16);
            atomicAdd(&s_B[4], cp);
        }
    }
    __syncthreads();                               // B3
    if (tid == 0) {
        if (s_B[4] < (uint32_t)K) {
            s_mode = 1;                            // < K positives
        } else {
            uint32_t cum = 0; int jf = -1;
            #pragma unroll
            for (int j = 0; j < 4; ++j) {
                cum += s_B[j];
                if (jf < 0 && cum >= (uint32_t)K) {
                    jf = j; s_C = cum; s_ecut = expM - (uint32_t)j;
                }
            }
            if (jf < 0) s_mode = 2;                // window too small: widen
        }
    }
    __syncthreads();                               // B4

    if (s_mode == 1) {                             // pass-through
        #pragma unroll
        for (int j = 0; j < V4; ++j) {
            float4 o;
            o.x = __uint_as_float(v[4*j+0]); o.y = __uint_as_float(v[4*j+1]);
            o.z = __uint_as_float(v[4*j+2]); o.w = __uint_as_float(v[4*j+3]);
            outp[tid + j * BLOCK] = o;
        }
        return;
    }

    if (s_mode == 2) {                             // cold: widen exponent cut
        uint32_t ec = (expM > 7u) ? (expM - 7u) : 0u;
        for (;;) {
            __syncthreads();
            uint32_t lc = 0;
            #pragma unroll
            for (int j = 0; j < VPT; ++j)
                lc += (v[j] != 0u && (v[j] >> 23) >= ec) ? 1u : 0u;
            lc = wave_reduce_add(lc);
            if (lane == 0) s_wred[wave] = lc;
            __syncthreads();
            if (tid == 0) {
                uint32_t c = 0;
                #pragma unroll
                for (int w = 0; w < 8; ++w) c += s_wred[w];
                s_C = c; s_ecut = ec;
            }
            __syncthreads();
            if (s_C >= (uint32_t)K || ec == 0u) break;
            ec = (ec > 8u) ? (ec - 8u) : 0u;
        }
    }
    const uint32_t C    = s_C;
    const uint32_t ecut = s_ecut;

    if (C <= (uint32_t)CAP) {
        // ---- hot path: compact candidates, all-pairs rank select ----
        uint32_t lc = 0;
        #pragma unroll
        for (int j = 0; j < VPT; ++j)
            lc += (v[j] != 0u && (v[j] >> 23) >= ecut) ? 1u : 0u;
        uint32_t incl = lc;
        #pragma unroll
        for (int d = 1; d < 64; d <<= 1) {
            uint32_t t = __shfl_up(incl, d, 64);
            if (lane >= d) incl += t;
        }
        uint32_t baseV = 0;
        if (lane == 63) baseV = atomicAdd(&s_listcnt, incl);  // 1 atomic/wave
        uint32_t base = __shfl(baseV, 63, 64);
        uint32_t pos  = base + (incl - lc);
        #pragma unroll
        for (int j = 0; j < VPT; ++j) {
            uint32_t x = v[j];
            if (x != 0u && (x >> 23) >= ecut) list[pos++] = x;
        }
        const uint32_t Cp = (C + 3u) & ~3u;        // pad to uint4 multiple
        for (uint32_t i = C + tid; i < Cp; i += BLOCK) list[i] = 0u;
        __syncthreads();                           // B5

        uint32_t x0 = (tid < (int)C)          ? list[tid]          : 0u;
        uint32_t x1 = (tid + BLOCK < (int)C)  ? list[tid + BLOCK]  : 0u;
        uint32_t c0 = 0, c1 = 0;
        const uint4* l4 = reinterpret_cast<const uint4*>(list);
        const uint32_t n4 = Cp >> 2;
        for (uint32_t i = 0; i < n4; ++i) {        // same-addr LDS broadcast
            uint4 y = l4[i];
            c0 += (y.x > x0) + (y.y > x0) + (y.z > x0) + (y.w > x0);
            c1 += (y.x > x1) + (y.y > x1) + (y.z > x1) + (y.w > x1);
        }
        // T = min{x in list : #greater < K}; need = K - #greater(T)
        if (x0 != 0u && c0 < (uint32_t)K) atomicMin(&s_T, x0);
        if (x1 != 0u && c1 < (uint32_t)K) atomicMin(&s_T, x1);
        __syncthreads();                           // B6
        const uint32_t Tv = s_T;
        if (x0 == Tv && x0 != 0u) s_need = (uint32_t)K - c0;  // benign same-value race
        if (x1 == Tv && x1 != 0u) s_need = (uint32_t)K - c1;
        __syncthreads();                           // B7
    } else {
        // ---- cold path: full-register 4x8-bit radix (contended, rare) ----
        if (tid == 0) { s_T = 0; s_need = K; }
        if (tid < 256) { hist[0][tid]=0; hist[1][tid]=0; hist[2][tid]=0; hist[3][tid]=0; }
        __syncthreads();
        #pragma unroll
        for (int j = 0; j < VPT; ++j) {
            uint32_t x = v[j];
            if (x) atomicAdd(&hist[wave & 3][x >> 24], 1u);
        }
        __syncthreads();
        if (tid < 256)
            hist[0][tid] = hist[0][tid] + hist[1][tid] + hist[2][tid] + hist[3][tid];
        __syncthreads();
        if (wave == 0) scan_pick(hist[0], &s_T, &s_need, 24, lane);
        __syncthreads();

        for (int shift = 16; shift >= 0; shift -= 8) {
            const uint32_t prefix = s_T;
            if (tid < 256) { hist[0][tid]=0; hist[1][tid]=0; hist[2][tid]=0; hist[3][tid]=0; }
            __syncthreads();
            const uint32_t himask = 0xFFFFFFFFu << (shift + 8);
            #pragma unroll
            for (int j = 0; j < VPT; ++j) {
                uint32_t x = v[j];
                if ((x & himask) == prefix)
                    atomicAdd(&hist[wave & 3][(x >> shift) & 255u], 1u);
            }
            __syncthreads();
            if (tid < 256)
                hist[0][tid] = hist[0][tid] + hist[1][tid] + hist[2][tid] + hist[3][tid];
            __syncthreads();
            if (wave == 0) scan_pick(hist[0], &s_T, &s_need, shift, lane);
            __syncthreads();
        }
    }

    // ---- output: keep x > T; among x == T keep `need` lowest indices ----
    const uint32_t T    = s_T;
    const uint32_t need = s_need;
    const float    Tf   = __uint_as_float(T);

    #pragma unroll
    for (int j = 0; j < V4; ++j) {
        const int base = (tid + j * BLOCK) * 4;
        float4 o;
        float* oc = &o.x;
        #pragma unroll
        for (int c = 0; c < 4; ++c) {
            uint32_t x = v[4*j+c];
            float val = 0.f;
            if (x > T) {
                val = __uint_as_float(x);
            } else if (x == T) {
                uint32_t p = atomicAdd(&s_cnt, 1u);
                if (p < (uint32_t)EQ_CAP) s_eq[p] = (uint32_t)(base + c);
            }
            oc[c] = val;
        }
        outp[tid + j * BLOCK] = o;
    }
    __syncthreads();                               // B8

    if (tid == 0) {
        uint32_t cnt = s_cnt < (uint32_t)EQ_CAP ? s_cnt : (uint32_t)EQ_CAP;
        for (uint32_t n = 0; n < need; ++n) {      // need is typically 1
            uint32_t best = 0xFFFFFFFFu, bi = 0;
            for (uint32_t i = 0; i < cnt; ++i)
                if (s_eq[i] < best) { best = s_eq[i]; bi = i; }
            if (best != 0xFFFFFFFFu) {
                s_eq[bi] = 0xFFFFFFFFu;
                out[(size_t)row * N + best] = Tf;
            }
        }
    }
}

extern "C" void kernel_launch(void* const* d_in, const int* in_sizes, int n_in,
                              void* d_out, int out_size, void* d_ws, size_t ws_size,
                              hipStream_t stream) {
    const float* A = (const float*)d_in[0];   // 8192*8192 fp32
    // d_in[1] (idx) is unused by the reference.
    float* out = (float*)d_out;
    topk_row_kernel<<<N, BLOCK, 0, stream>>>(A, out);
}